// Round 11
// baseline (223.455 us; speedup 1.0000x reference)
//
#include <hip/hip_runtime.h>
#include <math.h>

#define B_ 2
#define L_ 2048
#define D_ 512
#define H_ 8
#define E_ 64
#define CHUNK 32
#define NCH 64                 // L_/CHUNK
#define DEN_EPS_ 1e-5f
#define LN_EPS_ 1e-5f
#define NBLK 256

typedef __bf16 bf16x8 __attribute__((ext_vector_type(8)));
typedef __bf16 bf16x4 __attribute__((ext_vector_type(4)));
typedef float  f32x4  __attribute__((ext_vector_type(4)));

__device__ __forceinline__ float sigm(float x) { return 1.f / (1.f + expf(-x)); }
__device__ __forceinline__ float elu1(float x) { return x > 0.f ? x + 1.f : expf(x); }

__device__ __forceinline__ void async_cp16(const void* g, void* l) {
    __builtin_amdgcn_global_load_lds(
        (const __attribute__((address_space(1))) void*)g,
        (__attribute__((address_space(3))) void*)l, 16, 0, 0);
}

#define SWZ4(row, q) ((((q) ^ ((row) & 3)) * 8))

// manual grid barrier: counters pre-zeroed via hipMemsetAsync on the stream.
// 256 blocks are always co-resident (57KB LDS: even 2-per-CU packing fits),
// so the spin cannot deadlock.
__device__ __forceinline__ void gbar(unsigned int* bar, int idx) {
    __syncthreads();
    if (threadIdx.x == 0) {
        __threadfence();                       // release: flush to device level
        atomicAdd(&bar[idx], 1u);              // device-scope
        while (__hip_atomic_load(&bar[idx], __ATOMIC_RELAXED,
                                 __HIP_MEMORY_SCOPE_AGENT) < (unsigned)NBLK)
            __builtin_amdgcn_s_sleep(8);
        __threadfence();                       // acquire
    }
    __syncthreads();
}

// ---- phase-overlaid shared structs ----
struct AttnS {
    __bf16 Qw[32][64];
    __bf16 Kw[32][64];
    __bf16 Vt[64][40];
    __bf16 A1[32][40];
    float  den[32];
    float  zz[64];
};
struct OutS {
    __bf16 lds[16896];          // A 16x32 = 512, B 512x32 = 16384
    float  gaml[512], betl[512], bl[512];
    float  redS[4][16], redQ[4][16];
    float  mv[16][2];
};

// ---------------------------------------------------------------------------
// Mega-kernel: prep -> qkv+G -> scan -> attn -> out+LN, manual grid barriers.
// 256 blocks x 256 threads (co-resident by construction).
// ---------------------------------------------------------------------------
__global__ __launch_bounds__(256) void k_mega(
    const float* __restrict__ X,  const float* __restrict__ W1,
    const float* __restrict__ W2, const float* __restrict__ bqkv,
    const float* __restrict__ bout, const float* __restrict__ gam,
    const float* __restrict__ bet,  const float* __restrict__ dl,
    __bf16* __restrict__ WqkvT, __bf16* __restrict__ WoutT,
    __bf16* __restrict__ Qb, __bf16* __restrict__ Kb, __bf16* __restrict__ Vb,
    __bf16* __restrict__ Gt, float* __restrict__ gn,
    __bf16* __restrict__ Sb, float* __restrict__ zl,
    __bf16* __restrict__ Ao, float* __restrict__ out,
    unsigned int* bar)
{
    __shared__ __align__(16) char smem[57344];
    const int t  = threadIdx.x;
    const int vb = blockIdx.x;
    const int w = t >> 6, lane = t & 63;
    const int ll = lane & 15, quad = lane >> 4;

    // ================= Phase 0: weight transpose+convert =================
    {
        __bf16 (*tile)[68] = (__bf16(*)[68])smem;
        const int xt_ = vb & 31, ky = vb >> 5;
        const float* src; __bf16* dst; int N, xt;
        if (xt_ < 24) { src = W1; dst = WqkvT; N = 1536; xt = xt_; }
        else          { src = W2; dst = WoutT; N = 512;  xt = xt_ - 24; }
        const int K = 512;
        const int kb = ky * 64, nb = xt * 64;
        const int rr = t >> 4, cc4 = (t & 15) * 4;
#pragma unroll
        for (int p = 0; p < 4; p++) {
            int k = rr + p * 16;
            float4 v = *(const float4*)&src[(size_t)(kb + k) * N + nb + cc4];
            tile[k][cc4 + 0] = (__bf16)v.x;
            tile[k][cc4 + 1] = (__bf16)v.y;
            tile[k][cc4 + 2] = (__bf16)v.z;
            tile[k][cc4 + 3] = (__bf16)v.w;
        }
        __syncthreads();
#pragma unroll
        for (int p = 0; p < 4; p++) {
            int n = rr + p * 16;
            bf16x4 o;
            o[0] = tile[cc4 + 0][n];
            o[1] = tile[cc4 + 1][n];
            o[2] = tile[cc4 + 2][n];
            o[3] = tile[cc4 + 3][n];
            *(bf16x4*)&dst[(size_t)(nb + n) * K + kb + cc4] = o;
        }
    }
    gbar(bar, 0);

    // ================= Phase 1: qkv GEMM + featurize + chunk G ============
    {
        __bf16* lds = (__bf16*)smem;   // dbuf {A[0,2048) B[2048,14336)} x2
        const int wm = w >> 1, wn = w & 1;
        const int m0 = (vb >> 2) * 64, n0 = (vb & 3) * 128;
        const int h0 = n0 >> 6;

        f32x4 acc[3][2][4] = {};
        const int sr = t >> 2;
        const int c4 = t & 3;
        const int skz = ((c4 ^ (sr & 3)) * 8);

        float4 pa0, pa1;
        auto fetchA = [&](int k0) {
            const float* ap = X + (size_t)(m0 + sr) * D_ + k0 + skz;
            pa0 = *(const float4*)ap;
            pa1 = *(const float4*)(ap + 4);
        };
        auto issueB = [&](int k0, int buf) {
            const int bb = buf * 14336 + 2048;
#pragma unroll
            for (int s = 0; s < 3; s++)
#pragma unroll
                for (int half = 0; half < 2; half++)
                    async_cp16(&WqkvT[(size_t)(s * 512 + n0 + half * 64 + sr) * D_ + k0 + skz],
                               &lds[bb + s * 4096 + (half * 64 + w * 16) * 32]);
        };
        auto writeA = [&](int buf) {
            bf16x8 o;
            o[0] = (__bf16)pa0.x; o[1] = (__bf16)pa0.y;
            o[2] = (__bf16)pa0.z; o[3] = (__bf16)pa0.w;
            o[4] = (__bf16)pa1.x; o[5] = (__bf16)pa1.y;
            o[6] = (__bf16)pa1.z; o[7] = (__bf16)pa1.w;
            *(bf16x8*)&lds[buf * 14336 + sr * 32 + c4 * 8] = o;
        };

        fetchA(0);
        issueB(0, 0);
        writeA(0);
        __syncthreads();

        for (int k0 = 0; k0 < D_; k0 += 32) {
            const int buf = (k0 >> 5) & 1, nbuf = buf ^ 1;
            const int nk = k0 + 32;
            if (nk < D_) { fetchA(nk); issueB(nk, nbuf); }
            const int ao = buf * 14336, bo = ao + 2048;
            bf16x8 afr[2];
#pragma unroll
            for (int im = 0; im < 2; im++) {
                int ra = wm * 32 + im * 16 + ll;
                afr[im] = *(const bf16x8*)&lds[ao + ra * 32 + SWZ4(ra, quad)];
            }
#pragma unroll
            for (int s = 0; s < 3; s++) {
                bf16x8 bfr[4];
#pragma unroll
                for (int in = 0; in < 4; in++) {
                    int rb = wn * 64 + in * 16 + ll;
                    bfr[in] = *(const bf16x8*)&lds[bo + s * 4096 + rb * 32 + SWZ4(rb, quad)];
                }
#pragma unroll
                for (int im = 0; im < 2; im++)
#pragma unroll
                    for (int in = 0; in < 4; in++)
                        acc[s][im][in] = __builtin_amdgcn_mfma_f32_16x16x32_bf16(
                            afr[im], bfr[in], acc[s][im][in], 0, 0, 0);
            }
            if (nk < D_) writeA(nbuf);
            __syncthreads();
        }

        const int h = h0 + wn;
        const float lam = sigm(dl[h]);
        const float l2  = log2f(lam);
        __bf16* Kwt = &lds[w * 4096];
        __bf16* Vtw = &lds[w * 4096 + 2048];

        float wk8[2][4];
#pragma unroll
        for (int im = 0; im < 2; im++)
#pragma unroll
            for (int r = 0; r < 4; r++) {
                int i = (im * 16 + quad * 4 + r) & 31;
                wk8[im][r] = exp2f(l2 * (float)(CHUNK - 1 - i));
            }

#pragma unroll
        for (int im = 0; im < 2; im++) {
#pragma unroll
            for (int in = 0; in < 4; in++) {
                int nc = wn * 64 + in * 16 + ll;
                int e  = nc & 63;
                float bq = bqkv[n0 + nc];
                float bk = bqkv[512 + n0 + nc];
                float bv = bqkv[1024 + n0 + nc];
#pragma unroll
                for (int r = 0; r < 4; r++) {
                    int mr = wm * 32 + im * 16 + quad * 4 + r;
                    int m = m0 + mr, bb2 = m >> 11, l = m & 2047;
                    size_t off = ((size_t)((bb2 * H_ + h) * L_ + l)) * E_ + e;
                    float vq = elu1(acc[0][im][in][r] + bq) * 0.125f;
                    float vk = elu1(acc[1][im][in][r] + bk);
                    float vv = acc[2][im][in][r] + bv;
                    Qb[off] = (__bf16)vq;
                    Kb[off] = (__bf16)vk;
                    Vb[off] = (__bf16)vv;
                    int i = mr & 31;
                    int col = ((i >> 3) ^ (e & 3)) * 8 + (i & 7);
                    Kwt[e * 32 + col] = (__bf16)(vk * wk8[im][r]);
                    Vtw[e * 32 + col] = (__bf16)vv;
                }
            }
        }

        const int bb2 = m0 >> 11;
        const int bh = bb2 * H_ + h;
        const int nchunk = ((m0 & 2047) >> 5) + wm;

        {
            float ga = 0.f;
#pragma unroll
            for (int ci = 0; ci < 4; ci++) {
                int colb = ((ci ^ (lane & 3)) * 8);
#pragma unroll
                for (int j = 0; j < 8; j++) ga += (float)Kwt[lane * 32 + colb + j];
            }
            gn[((size_t)bh * NCH + nchunk) * E_ + lane] = ga;
        }

        f32x4 gac[4][4] = {};
#pragma unroll
        for (int a = 0; a < 4; a++) {
            int raf = a * 16 + ll;
            bf16x8 av = *(const bf16x8*)&Vtw[raf * 32 + SWZ4(raf, quad)];
#pragma unroll
            for (int b2 = 0; b2 < 4; b2++) {
                int rbe = b2 * 16 + ll;
                bf16x8 kv = *(const bf16x8*)&Kwt[rbe * 32 + SWZ4(rbe, quad)];
                gac[a][b2] = __builtin_amdgcn_mfma_f32_16x16x32_bf16(av, kv, gac[a][b2], 0, 0, 0);
            }
        }
        size_t gbase = ((size_t)bh * NCH + nchunk) * 4096;
#pragma unroll
        for (int a = 0; a < 4; a++)
#pragma unroll
            for (int b2 = 0; b2 < 4; b2++)
#pragma unroll
                for (int r = 0; r < 4; r++) {
                    int f = a * 16 + quad * 4 + r;
                    int e = b2 * 16 + ll;
                    Gt[gbase + (size_t)f * 64 + e] = (__bf16)gac[a][b2][r];
                }
    }
    gbar(bar, 1);

    // ================= Phase 2: chunk scan (4 wave-units/block) ===========
    {
        const int unit = vb * 4 + w;            // 0..1023
        const int bh = unit >> 6;
        const int j  = unit & 63;
        const float lam = sigm(dl[bh & 7]);
        const float dC  = exp2f(32.f * log2f(lam));

        const size_t base = ((size_t)bh * NCH) * 4096 + (size_t)j * 64 + lane;

        __bf16 g[NCH];
#pragma unroll
        for (int n = 0; n < NCH; n++) g[n] = Gt[base + (size_t)n * 4096];

        float s = 0.f;
#pragma unroll
        for (int n = 0; n < NCH; n++) {
            Sb[base + (size_t)n * 4096] = (__bf16)(lam * s);
            s = fmaf(dC, s, (float)g[n]);
        }

        float gv = gn[((size_t)bh * NCH + lane) * E_ + j];
        float wf = dC;
#pragma unroll
        for (int k = 1; k < 64; k <<= 1) {
            float up = __shfl_up(gv, k);
            if (lane >= k) gv = fmaf(wf, up, gv);
            wf = wf * wf;
        }
        float zex = __shfl_up(gv, 1);
        if (lane == 0) zex = 0.f;
        zl[((size_t)bh * NCH + lane) * E_ + j] = lam * zex;
    }
    gbar(bar, 2);

    // ================= Phase 3: attention (4 units/block, sequential) =====
    {
        AttnS& S = *(AttnS*)smem;
        for (int u = 0; u < 4; u++) {
            const int bx = vb * 4 + u;
            const int n = bx & 63, h = (bx >> 6) & 7, bb = bx >> 9;
            const int bh = bb * H_ + h;
            const float lam = sigm(dl[h]);
            const float l2  = log2f(lam);
            const int fw = w * 16;
            const size_t sbase = ((size_t)bh * NCH + n) * 4096;

            bf16x8 bS0 = *(const bf16x8*)&Sb[sbase + (size_t)(fw + ll) * 64 + quad * 8];
            bf16x8 bS1 = *(const bf16x8*)&Sb[sbase + (size_t)(fw + ll) * 64 + 32 + quad * 8];

            {
                int i = t >> 3, e0c = t & 7;
                size_t src = ((size_t)bh * L_ + n * CHUNK + i) * E_ + e0c * 8;
                float wq = exp2f(l2 * (float)i);
                float wk = exp2f(-l2 * (float)i);
                bf16x8 q8 = *(const bf16x8*)&Qb[src];
                bf16x8 k8 = *(const bf16x8*)&Kb[src];
                bf16x8 v8 = *(const bf16x8*)&Vb[src];
                bf16x8 qo, ko;
                int e0 = e0c * 8;
#pragma unroll
                for (int q = 0; q < 8; q++) {
                    qo[q] = (__bf16)((float)q8[q] * wq);
                    ko[q] = (__bf16)((float)k8[q] * wk);
                    S.Vt[e0 + q][i] = v8[q];
                }
                int cs = (e0c ^ (i & 7)) * 8;
                *(bf16x8*)&S.Qw[i][cs] = qo;
                *(bf16x8*)&S.Kw[i][cs] = ko;
                if (t < 64) S.zz[t] = zl[((size_t)bh * NCH + n) * E_ + t];
            }
            __syncthreads();

            {
                const int wm = w >> 1, wn = w & 1;
                int ra = wm * 16 + ll, rb = wn * 16 + ll;
                f32x4 accA = {};
#pragma unroll
                for (int ks = 0; ks < 2; ks++) {
                    bf16x8 a = *(const bf16x8*)&S.Qw[ra][((ks * 4 + quad) ^ (ra & 7)) * 8];
                    bf16x8 b = *(const bf16x8*)&S.Kw[rb][((ks * 4 + quad) ^ (rb & 7)) * 8];
                    accA = __builtin_amdgcn_mfma_f32_16x16x32_bf16(a, b, accA, 0, 0, 0);
                }
                int j = wn * 16 + ll;
#pragma unroll
                for (int r = 0; r < 4; r++) {
                    int i = wm * 16 + quad * 4 + r;
                    S.A1[i][j] = (__bf16)(j <= i ? accA[r] : 0.f);
                }
            }
            __syncthreads();

            if (t < 32) {
                float rs = 0.f;
#pragma unroll
                for (int k8 = 0; k8 < 4; k8++) {
                    bf16x8 aa = *(const bf16x8*)&S.A1[t][k8 * 8];
#pragma unroll
                    for (int q = 0; q < 8; q++) rs += (float)aa[q];
                }
                float qz = 0.f;
#pragma unroll
                for (int e8 = 0; e8 < 8; e8++) {
                    bf16x8 qq = *(const bf16x8*)&S.Qw[t][(e8 ^ (t & 7)) * 8];
#pragma unroll
                    for (int q = 0; q < 8; q++) qz += (float)qq[q] * S.zz[e8 * 8 + q];
                }
                S.den[t] = rs + qz + DEN_EPS_;
            }

            f32x4 acc1[2] = {}, acc2[2] = {};
            {
                bf16x8 bV = *(const bf16x8*)&S.Vt[fw + ll][quad * 8];
#pragma unroll
                for (int im = 0; im < 2; im++) {
                    bf16x8 aA = *(const bf16x8*)&S.A1[im * 16 + ll][quad * 8];
                    acc1[im] = __builtin_amdgcn_mfma_f32_16x16x32_bf16(aA, bV, acc1[im], 0, 0, 0);
                }
#pragma unroll
                for (int im = 0; im < 2; im++) {
                    int ra = im * 16 + ll;
                    bf16x8 aQ0 = *(const bf16x8*)&S.Qw[ra][((quad) ^ (ra & 7)) * 8];
                    bf16x8 aQ1 = *(const bf16x8*)&S.Qw[ra][((4 + quad) ^ (ra & 7)) * 8];
                    acc2[im] = __builtin_amdgcn_mfma_f32_16x16x32_bf16(aQ0, bS0, acc2[im], 0, 0, 0);
                    acc2[im] = __builtin_amdgcn_mfma_f32_16x16x32_bf16(aQ1, bS1, acc2[im], 0, 0, 0);
                }
            }
            __syncthreads();

#pragma unroll
            for (int im = 0; im < 2; im++)
#pragma unroll
                for (int r = 0; r < 4; r++) {
                    int i = im * 16 + quad * 4 + r;
                    float o = (acc1[im][r] + acc2[im][r]) / S.den[i];
                    Ao[((size_t)bb * L_ + n * CHUNK + i) * D_ + h * E_ + fw + ll] = (__bf16)o;
                }
            __syncthreads();
        }
    }
    gbar(bar, 3);

    // ================= Phase 4: out GEMM + LayerNorm ======================
    {
        OutS& S = *(OutS*)smem;
        const int m0 = vb * 16;

        {
            float2 g = *(const float2*)&gam[t * 2];
            float2 b2 = *(const float2*)&bet[t * 2];
            float2 bo = *(const float2*)&bout[t * 2];
            S.gaml[t * 2] = g.x;  S.gaml[t * 2 + 1] = g.y;
            S.betl[t * 2] = b2.x; S.betl[t * 2 + 1] = b2.y;
            S.bl[t * 2]   = bo.x; S.bl[t * 2 + 1]   = bo.y;
        }

        f32x4 acc[8] = {};
        const int sr  = t >> 2;
        const int skz = (((t & 3) ^ (sr & 3)) * 8);

        for (int k0 = 0; k0 < D_; k0 += 32) {
            if (t < 64)
                async_cp16(&Ao[(size_t)(m0 + sr) * D_ + k0 + skz], &S.lds[0]);
#pragma unroll
            for (int p = 0; p < 8; p++)
                async_cp16(&WoutT[(size_t)(p * 64 + sr) * D_ + k0 + skz],
                           &S.lds[512 + (p * 64 + w * 16) * 32]);
            __syncthreads();
            bf16x8 a = *(const bf16x8*)&S.lds[ll * 32 + SWZ4(ll, quad)];
#pragma unroll
            for (int in = 0; in < 8; in++) {
                int rb = w * 128 + in * 16 + ll;
                bf16x8 b = *(const bf16x8*)&S.lds[512 + rb * 32 + SWZ4(rb, quad)];
                acc[in] = __builtin_amdgcn_mfma_f32_16x16x32_bf16(a, b, acc[in], 0, 0, 0);
            }
            __syncthreads();
        }

        float vals[8][4];
        float ps[4] = {}, pq[4] = {};
#pragma unroll
        for (int in = 0; in < 8; in++) {
            int col = w * 128 + in * 16 + ll;
            float bv = S.bl[col];
#pragma unroll
            for (int r = 0; r < 4; r++) {
                float v = acc[in][r] + bv;
                vals[in][r] = v;
                ps[r] += v;
                pq[r] += v * v;
            }
        }
#pragma unroll
        for (int r = 0; r < 4; r++) {
            float s = ps[r], q = pq[r];
            s += __shfl_xor(s, 1); q += __shfl_xor(q, 1);
            s += __shfl_xor(s, 2); q += __shfl_xor(q, 2);
            s += __shfl_xor(s, 4); q += __shfl_xor(q, 4);
            s += __shfl_xor(s, 8); q += __shfl_xor(q, 8);
            if (ll == 0) {
                int row = quad * 4 + r;
                S.redS[w][row] = s;
                S.redQ[w][row] = q;
            }
        }
        __syncthreads();
        if (t < 16) {
            float Su = S.redS[0][t] + S.redS[1][t] + S.redS[2][t] + S.redS[3][t];
            float Qu = S.redQ[0][t] + S.redQ[1][t] + S.redQ[2][t] + S.redQ[3][t];
            float mu  = Su * (1.f / 512.f);
            float var = Qu * (1.f / 512.f) - mu * mu;
            S.mv[t][0] = mu;
            S.mv[t][1] = rsqrtf(var + LN_EPS_);
        }
        __syncthreads();
#pragma unroll
        for (int r = 0; r < 4; r++) {
            int row = quad * 4 + r;
            float mu = S.mv[row][0], rs = S.mv[row][1];
#pragma unroll
            for (int in = 0; in < 8; in++) {
                int col = w * 128 + in * 16 + ll;
                out[(size_t)(m0 + row) * D_ + col] =
                    (vals[in][r] - mu) * rs * S.gaml[col] + S.betl[col];
            }
        }
    }
}

// ---------------------------------------------------------------------------
extern "C" void kernel_launch(void* const* d_in, const int* in_sizes, int n_in,
                              void* d_out, int out_size, void* d_ws, size_t ws_size,
                              hipStream_t stream)
{
    const float* x    = (const float*)d_in[0];
    const float* Wqkv = (const float*)d_in[1];
    const float* bqkv = (const float*)d_in[2];
    const float* Wout = (const float*)d_in[3];
    const float* bout = (const float*)d_in[4];
    const float* gam  = (const float*)d_in[5];
    const float* bet  = (const float*)d_in[6];
    const float* dl   = (const float*)d_in[7];
    float* out = (float*)d_out;

    const size_t NBHLE = (size_t)B_ * H_ * L_ * E_;       // 2,097,152
    const size_t NG    = (size_t)B_ * H_ * NCH * E_ * E_; // 4,194,304
    const size_t Ng    = (size_t)B_ * H_ * NCH * E_;      // 65,536

    char* p = (char*)d_ws;
    unsigned int* bar = (unsigned int*)p;  p += 256;       // 4 counters + pad
    __bf16* Gt  = (__bf16*)p;    p += NG * 2;
    __bf16* Sb  = (__bf16*)p;    p += NG * 2;
    float*  gn  = (float*)p;     p += Ng * 4;
    float*  zl  = (float*)p;     p += Ng * 4;
    __bf16* Qb  = (__bf16*)p;    p += NBHLE * 2;
    __bf16* Kb  = (__bf16*)p;    p += NBHLE * 2;
    __bf16* Vb  = (__bf16*)p;    p += NBHLE * 2;
    __bf16* WqkvT = (__bf16*)p;  p += (size_t)1536 * 512 * 2;
    __bf16* WoutT = (__bf16*)p;  p += (size_t)512 * 512 * 2;
    __bf16* Ao    = (__bf16*)p;  p += NBHLE * 2;

    hipMemsetAsync(bar, 0, 4 * sizeof(unsigned int), stream);
    k_mega<<<dim3(NBLK), dim3(256), 0, stream>>>(
        x, Wqkv, Wout, bqkv, bout, gam, bet, dl,
        WqkvT, WoutT, Qb, Kb, Vb, Gt, gn, Sb, zl, Ao, out, bar);
}

// Round 12
// 127.126 us; speedup vs baseline: 1.7577x; 1.7577x over previous
//
#include <hip/hip_runtime.h>
#include <math.h>

#define B_ 2
#define L_ 2048
#define D_ 512
#define H_ 8
#define E_ 64
#define CHUNK 32
#define NCH 64                 // L_/CHUNK
#define DEN_EPS_ 1e-5f
#define LN_EPS_ 1e-5f

typedef __bf16 bf16x8 __attribute__((ext_vector_type(8)));
typedef __bf16 bf16x4 __attribute__((ext_vector_type(4)));
typedef float  f32x4  __attribute__((ext_vector_type(4)));

__device__ __forceinline__ float sigm(float x) { return 1.f / (1.f + expf(-x)); }
__device__ __forceinline__ float elu1(float x) { return x > 0.f ? x + 1.f : expf(x); }

// async global->LDS 16B/lane; LDS dest = wave-uniform base + lane*16
__device__ __forceinline__ void async_cp16(const void* g, void* l) {
    __builtin_amdgcn_global_load_lds(
        (const __attribute__((address_space(1))) void*)g,
        (__attribute__((address_space(3))) void*)l, 16, 0, 0);
}

// BK=32 tiles: 4 chunks of 8 bf16 per row; chunk swizzle kills bank conflicts
#define SWZ4(row, q) ((((q) ^ ((row) & 3)) * 8))

// ---------------------------------------------------------------------------
// Prep (weights only): fp32 [K][N] -> bf16 [N][K].  grid(32,8):
// x<24 -> Wqkv tile x ; x>=24 -> Wout tile x-24
// ---------------------------------------------------------------------------
__global__ __launch_bounds__(256) void k_prep_w(
    const float* __restrict__ W1, __bf16* __restrict__ D1,
    const float* __restrict__ W2, __bf16* __restrict__ D2)
{
    const int t = threadIdx.x;
    const int bx = blockIdx.x;
    const float* src; __bf16* dst; int N, xt;
    if (bx < 24) { src = W1; dst = D1; N = 1536; xt = bx; }
    else         { src = W2; dst = D2; N = 512;  xt = bx - 24; }
    const int K = 512;

    __shared__ __bf16 tile[64][68];
    const int kb = blockIdx.y * 64, nb = xt * 64;
    const int rr = t >> 4, cc4 = (t & 15) * 4;
#pragma unroll
    for (int p = 0; p < 4; p++) {
        int k = rr + p * 16;
        float4 v = *(const float4*)&src[(size_t)(kb + k) * N + nb + cc4];
        tile[k][cc4 + 0] = (__bf16)v.x;
        tile[k][cc4 + 1] = (__bf16)v.y;
        tile[k][cc4 + 2] = (__bf16)v.z;
        tile[k][cc4 + 3] = (__bf16)v.w;
    }
    __syncthreads();
#pragma unroll
    for (int p = 0; p < 4; p++) {
        int n = rr + p * 16;
        bf16x4 o;
        o[0] = tile[cc4 + 0][n];
        o[1] = tile[cc4 + 1][n];
        o[2] = tile[cc4 + 2][n];
        o[3] = tile[cc4 + 3][n];
        *(bf16x4*)&dst[(size_t)(nb + n) * K + kb + cc4] = o;
    }
}

// ---------------------------------------------------------------------------
// MFMA GEMM 1: qkv = x @ WqkvT^T + bias; featurize; scatter bf16 Q/K/V.
// 64x128 tile (768 blocks = 3/CU), BK=32, double-buffered LDS pipeline.
// A from fp32 x (VGPR convert), B via global_load_lds.  Vectorized scatter.
// ---------------------------------------------------------------------------
__global__ __launch_bounds__(256) void k_mfma_qkv(
    const float* __restrict__ X, const __bf16* __restrict__ Bt,
    const float* __restrict__ bias,
    __bf16* __restrict__ Qb, __bf16* __restrict__ Kb, __bf16* __restrict__ Vb)
{
    // lds layout: A buf0 [0,2048), A buf1 [2048,4096),
    //             B buf0 [4096,8192), B buf1 [8192,12288)
    // epilogue overlay: out tile 64x132 = 8448 elems from 0
    __shared__ __bf16 lds[12288];
    const int t = threadIdx.x;
    const int w = t >> 6, lane = t & 63;
    const int wm = w >> 1, wn = w & 1;
    const int ll = lane & 15, quad = lane >> 4;
    const int m0 = blockIdx.y * 64, n0 = blockIdx.x * 128;

    f32x4 acc[2][4] = {};
    const int sr = t >> 2;                      // staging row 0..63
    const int c4 = t & 3;                       // LDS chunk
    const int gA = (c4 ^ (sr & 3));             // global chunk (swizzled)
    const int skz = gA * 8;

    float4 pa0, pa1;
    auto fetchA = [&](int k0) {
        const float* ap = X + (size_t)(m0 + sr) * D_ + k0 + skz;
        pa0 = *(const float4*)ap;
        pa1 = *(const float4*)(ap + 4);
    };
    auto issueB = [&](int k0, int nbuf) {
        __bf16* b0 = &lds[4096 + nbuf * 4096 + (w * 16) * 32];
        __bf16* b1 = &lds[4096 + nbuf * 4096 + (64 + w * 16) * 32];
        async_cp16(&Bt[(size_t)(n0 + sr) * D_ + k0 + skz],      b0);
        async_cp16(&Bt[(size_t)(n0 + 64 + sr) * D_ + k0 + skz], b1);
    };
    auto writeA = [&](int buf) {
        bf16x8 o;
        o[0] = (__bf16)pa0.x; o[1] = (__bf16)pa0.y;
        o[2] = (__bf16)pa0.z; o[3] = (__bf16)pa0.w;
        o[4] = (__bf16)pa1.x; o[5] = (__bf16)pa1.y;
        o[6] = (__bf16)pa1.z; o[7] = (__bf16)pa1.w;
        *(bf16x8*)&lds[buf * 2048 + sr * 32 + c4 * 8] = o;
    };

    fetchA(0);
    issueB(0, 0);
    writeA(0);
    __syncthreads();

    for (int k0 = 0; k0 < D_; k0 += 32) {
        const int buf = (k0 >> 5) & 1, nbuf = buf ^ 1;
        const int nk = k0 + 32;
        if (nk < D_) { fetchA(nk); issueB(nk, nbuf); }
        const int ao = buf * 2048, bo = 4096 + buf * 4096;
#pragma unroll
        for (int im = 0; im < 2; im++) {
            int ra = wm * 32 + im * 16 + ll;
            bf16x8 a = *(const bf16x8*)&lds[ao + ra * 32 + SWZ4(ra, quad)];
#pragma unroll
            for (int in = 0; in < 4; in++) {
                int rb = wn * 64 + in * 16 + ll;
                bf16x8 b = *(const bf16x8*)&lds[bo + rb * 32 + SWZ4(rb, quad)];
                acc[im][in] = __builtin_amdgcn_mfma_f32_16x16x32_bf16(a, b, acc[im][in], 0, 0, 0);
            }
        }
        if (nk < D_) writeA(nbuf);
        __syncthreads();
    }

    // epilogue: featurize into LDS (stride 132), then vectorized scatter
    const int sec = n0 >> 9;   // 0:q 1:k 2:v (uniform per block)
#pragma unroll
    for (int im = 0; im < 2; im++) {
#pragma unroll
        for (int in = 0; in < 4; in++) {
            int nc = wn * 64 + in * 16 + ll;
            float bv = bias[n0 + nc];
#pragma unroll
            for (int r = 0; r < 4; r++) {
                int mr = wm * 32 + im * 16 + quad * 4 + r;
                float v = acc[im][in][r] + bv;
                if (sec == 0)      v = elu1(v) * 0.125f;
                else if (sec == 1) v = elu1(v);
                lds[mr * 132 + nc] = (__bf16)v;
            }
        }
    }
    __syncthreads();

    __bf16* base = (sec == 0 ? Qb : (sec == 1 ? Kb : Vb));
    const int hbase = (n0 & 511) >> 6;
#pragma unroll
    for (int u = 0; u < 2; u++) {
        int id = u * 256 + t;
        int row = id >> 3;           // 0..63
        int c0  = (id & 7) * 16;     // 0..112
        bf16x8 v0 = *(bf16x8*)&lds[row * 132 + c0];
        bf16x8 v1 = *(bf16x8*)&lds[row * 132 + c0 + 8];
        int h = hbase + (c0 >> 6);
        int e0 = c0 & 63;
        int m = m0 + row, bb2 = m >> 11, l = m & 2047;
        __bf16* dst = base + ((size_t)((bb2 * H_ + h) * L_ + l)) * E_ + e0;
        *(bf16x8*)dst       = v0;
        *(bf16x8*)(dst + 8) = v1;
    }
}

// ---------------------------------------------------------------------------
// Chunk sums (MFMA): per (b,h,n)  Gt_n = V^T K_w  (stored [f][e], bf16),
//                    g_n[e] = sum_i K_w[i][e] (fp32)
// ---------------------------------------------------------------------------
__global__ __launch_bounds__(256) void k_chunk_g(
    const __bf16* __restrict__ Kb, const __bf16* __restrict__ Vb,
    const float* __restrict__ dl,
    __bf16* __restrict__ Gt, float* __restrict__ gn)
{
    __shared__ __bf16 Kwt[64][40];   // [e][i], weighted
    __shared__ __bf16 Vt[64][40];    // [f][i]
    const int t  = threadIdx.x;
    const int bx = blockIdx.x;
    const int n = bx & 63, h = (bx >> 6) & 7, bb = bx >> 9;
    const int bh = bb * H_ + h;
    const float lam = sigm(dl[h]);
    const float l2  = log2f(lam);

    {   // stage transposed
        int i = t & 31, e0 = (t >> 5) * 8;
        size_t src = ((size_t)bh * L_ + n * CHUNK + i) * E_ + e0;
        float wk = exp2f(l2 * (float)(CHUNK - 1 - i));
        bf16x8 k8 = *(const bf16x8*)&Kb[src];
        bf16x8 v8 = *(const bf16x8*)&Vb[src];
#pragma unroll
        for (int q = 0; q < 8; q++) {
            Kwt[e0 + q][i] = (__bf16)((float)k8[q] * wk);
            Vt[e0 + q][i]  = v8[q];
        }
    }
    __syncthreads();

    const int w = t >> 6, lane = t & 63;
    const int wm = w >> 1, wn = w & 1;
    const int ll = lane & 15, quad = lane >> 4;

    // A-operand rows = f (V), B-operand rows = e (Kw)  ->  C[f][e]
    bf16x8 af[2], bf_[2];
#pragma unroll
    for (int a = 0; a < 2; a++) {
        af[a]  = *(const bf16x8*)&Vt[wm * 32 + a * 16 + ll][quad * 8];
        bf_[a] = *(const bf16x8*)&Kwt[wn * 32 + a * 16 + ll][quad * 8];
    }
    f32x4 acc[2][2] = {};
#pragma unroll
    for (int a = 0; a < 2; a++)
#pragma unroll
        for (int b = 0; b < 2; b++)
            acc[a][b] = __builtin_amdgcn_mfma_f32_16x16x32_bf16(af[a], bf_[b], acc[a][b], 0, 0, 0);

    size_t gbase = ((size_t)bh * NCH + n) * 4096;
#pragma unroll
    for (int a = 0; a < 2; a++)
#pragma unroll
        for (int b = 0; b < 2; b++)
#pragma unroll
            for (int r = 0; r < 4; r++) {
                int f = wm * 32 + a * 16 + quad * 4 + r;
                int e = wn * 32 + b * 16 + ll;
                Gt[gbase + (size_t)f * 64 + e] = (__bf16)acc[a][b][r];
            }

    if (t < 64) {
        float ga = 0.f;
#pragma unroll
        for (int k8 = 0; k8 < 4; k8++) {
            bf16x8 kk = *(const bf16x8*)&Kwt[t][k8 * 8];
#pragma unroll
            for (int q = 0; q < 8; q++) ga += (float)kk[q];
        }
        gn[((size_t)bh * NCH + n) * E_ + t] = ga;
    }
}

// ---------------------------------------------------------------------------
// Scan: block (bh,f); lane = e.  64 independent loads -> in-register scan.
// z-scan via weighted Kogge-Stone.  Emits lam*S^T (bf16) and lam*z (fp32).
// ---------------------------------------------------------------------------
__global__ __launch_bounds__(64) void k_scan_par(
    const __bf16* __restrict__ Gt, const float* __restrict__ gn,
    const float* __restrict__ dl,
    __bf16* __restrict__ Sb, float* __restrict__ zl)
{
    const int lane = threadIdx.x;
    const int bh = blockIdx.x >> 6;
    const int j  = blockIdx.x & 63;          // f for S-scan, e for z-scan
    const float lam = sigm(dl[bh & 7]);
    const float dC  = exp2f(32.f * log2f(lam));

    const size_t base = ((size_t)bh * NCH) * 4096 + (size_t)j * 64 + lane;

    __bf16 g[NCH];
#pragma unroll
    for (int n = 0; n < NCH; n++) g[n] = Gt[base + (size_t)n * 4096];

    float s = 0.f;
#pragma unroll
    for (int n = 0; n < NCH; n++) {
        Sb[base + (size_t)n * 4096] = (__bf16)(lam * s);
        s = fmaf(dC, s, (float)g[n]);
    }

    // z-scan: lane = n
    float gv = gn[((size_t)bh * NCH + lane) * E_ + j];
    float wf = dC;
#pragma unroll
    for (int k = 1; k < 64; k <<= 1) {
        float up = __shfl_up(gv, k);
        if (lane >= k) gv = fmaf(wf, up, gv);
        wf = wf * wf;
    }
    float zex = __shfl_up(gv, 1);
    if (lane == 0) zex = 0.f;
    zl[((size_t)bh * NCH + lane) * E_ + j] = lam * zex;
}

// ---------------------------------------------------------------------------
// Attention (MFMA): per (b,h,n):
//   A = Qw Kw^T (masked);  O = A V + Qw S^T;  den = rowsum(A) + Qw.zz + eps
//   S fragments loaded DIRECTLY from global (L2); Qw/Kw swizzled in LDS.
// ---------------------------------------------------------------------------
__global__ __launch_bounds__(256) void k_attn(
    const __bf16* __restrict__ Qb, const __bf16* __restrict__ Kb,
    const __bf16* __restrict__ Vb,
    const __bf16* __restrict__ Sb, const float* __restrict__ zl,
    const float* __restrict__ dl, __bf16* __restrict__ Out)
{
    __shared__ __bf16 Qw[32][64];   // chunk-swizzled
    __shared__ __bf16 Kw[32][64];   // chunk-swizzled
    __shared__ __bf16 Vt[64][40];
    __shared__ __bf16 A1[32][40];
    __shared__ float  den[32];
    __shared__ float  zz[64];

    const int t  = threadIdx.x;
    const int bx = blockIdx.x;
    const int n = bx & 63, h = (bx >> 6) & 7, bb = bx >> 9;
    const int bh = bb * H_ + h;
    const float lam = sigm(dl[h]);
    const float l2  = log2f(lam);

    const int w = t >> 6, lane = t & 63;
    const int ll = lane & 15, quad = lane >> 4;
    const int fw = w * 16;
    const size_t sbase = ((size_t)bh * NCH + n) * 4096;

    // S B-fragments straight from global (issued first to hide L2 latency)
    bf16x8 bS0 = *(const bf16x8*)&Sb[sbase + (size_t)(fw + ll) * 64 + quad * 8];
    bf16x8 bS1 = *(const bf16x8*)&Sb[sbase + (size_t)(fw + ll) * 64 + 32 + quad * 8];

    {   // stage Q,K (weighted, swizzled), V (transposed)
        int i = t >> 3, e0c = t & 7;
        size_t src = ((size_t)bh * L_ + n * CHUNK + i) * E_ + e0c * 8;
        float wq = exp2f(l2 * (float)i);
        float wk = exp2f(-l2 * (float)i);
        bf16x8 q8 = *(const bf16x8*)&Qb[src];
        bf16x8 k8 = *(const bf16x8*)&Kb[src];
        bf16x8 v8 = *(const bf16x8*)&Vb[src];
        bf16x8 qo, ko;
        int e0 = e0c * 8;
#pragma unroll
        for (int q = 0; q < 8; q++) {
            qo[q] = (__bf16)((float)q8[q] * wq);
            ko[q] = (__bf16)((float)k8[q] * wk);
            Vt[e0 + q][i] = v8[q];
        }
        int cs = (e0c ^ (i & 7)) * 8;
        *(bf16x8*)&Qw[i][cs] = qo;
        *(bf16x8*)&Kw[i][cs] = ko;
        if (t < 64) zz[t] = zl[((size_t)bh * NCH + n) * E_ + t];
    }
    __syncthreads();

    // Phase A: each wave one 16x16 tile of the 32x32 A
    {
        const int wm = w >> 1, wn = w & 1;
        int ra = wm * 16 + ll, rb = wn * 16 + ll;
        f32x4 accA = {};
#pragma unroll
        for (int ks = 0; ks < 2; ks++) {
            bf16x8 a = *(const bf16x8*)&Qw[ra][((ks * 4 + quad) ^ (ra & 7)) * 8];
            bf16x8 b = *(const bf16x8*)&Kw[rb][((ks * 4 + quad) ^ (rb & 7)) * 8];
            accA = __builtin_amdgcn_mfma_f32_16x16x32_bf16(a, b, accA, 0, 0, 0);
        }
        int j = wn * 16 + ll;
#pragma unroll
        for (int r = 0; r < 4; r++) {
            int i = wm * 16 + quad * 4 + r;
            A1[i][j] = (__bf16)(j <= i ? accA[r] : 0.f);
        }
    }
    __syncthreads();

    // den  (Qw column chunk (e8 ^ (t&7)) holds e-range e8*8 -> pair with zz[e8*8+q])
    if (t < 32) {
        float rs = 0.f;
#pragma unroll
        for (int k8 = 0; k8 < 4; k8++) {
            bf16x8 aa = *(const bf16x8*)&A1[t][k8 * 8];
#pragma unroll
            for (int q = 0; q < 8; q++) rs += (float)aa[q];
        }
        float qz = 0.f;
#pragma unroll
        for (int e8 = 0; e8 < 8; e8++) {
            bf16x8 qq = *(const bf16x8*)&Qw[t][(e8 ^ (t & 7)) * 8];
#pragma unroll
            for (int q = 0; q < 8; q++) qz += (float)qq[q] * zz[e8 * 8 + q];
        }
        den[t] = rs + qz + DEN_EPS_;
    }

    // Phase O: wave w owns f-range [fw, fw+16)
    f32x4 acc1[2] = {}, acc2[2] = {};
    {
        bf16x8 bV = *(const bf16x8*)&Vt[fw + ll][quad * 8];
#pragma unroll
        for (int im = 0; im < 2; im++) {
            bf16x8 aA = *(const bf16x8*)&A1[im * 16 + ll][quad * 8];
            acc1[im] = __builtin_amdgcn_mfma_f32_16x16x32_bf16(aA, bV, acc1[im], 0, 0, 0);
        }
#pragma unroll
        for (int im = 0; im < 2; im++) {
            int ra = im * 16 + ll;
            bf16x8 aQ0 = *(const bf16x8*)&Qw[ra][((quad) ^ (ra & 7)) * 8];
            bf16x8 aQ1 = *(const bf16x8*)&Qw[ra][((4 + quad) ^ (ra & 7)) * 8];
            acc2[im] = __builtin_amdgcn_mfma_f32_16x16x32_bf16(aQ0, bS0, acc2[im], 0, 0, 0);
            acc2[im] = __builtin_amdgcn_mfma_f32_16x16x32_bf16(aQ1, bS1, acc2[im], 0, 0, 0);
        }
    }
    __syncthreads();

#pragma unroll
    for (int im = 0; im < 2; im++)
#pragma unroll
        for (int r = 0; r < 4; r++) {
            int i = im * 16 + quad * 4 + r;
            float o = (acc1[im][r] + acc2[im][r]) / den[i];
            Out[((size_t)bb * L_ + n * CHUNK + i) * D_ + h * E_ + fw + ll] = (__bf16)o;
        }
}

// ---------------------------------------------------------------------------
// MFMA GEMM 2 + fused LayerNorm: Y = LN(Ao @ WoutT^T + bout)
// 16x512 tile (256 blocks = 1/CU); double-buffered async staging.
// ---------------------------------------------------------------------------
__global__ __launch_bounds__(256) void k_mfma_out_ln(
    const __bf16* __restrict__ Ab, const __bf16* __restrict__ Bt,
    const float* __restrict__ bias, const float* __restrict__ gam,
    const float* __restrict__ bet, float* __restrict__ Y)
{
    // A buf0 [0,512), A buf1 [512,1024), B buf0 [1024,17408), B buf1 [17408,33792)
    __shared__ __bf16 lds[33792];
    __shared__ float gaml[512], betl[512], bl[512];
    __shared__ float redS[4][16], redQ[4][16];
    __shared__ float mv[16][2];

    const int t = threadIdx.x;
    const int w = t >> 6, lane = t & 63;
    const int ll = lane & 15, quad = lane >> 4;
    const int m0 = blockIdx.x * 16;

    {   // preload per-column params
        float2 g = *(const float2*)&gam[t * 2];
        float2 b2 = *(const float2*)&bet[t * 2];
        float2 bo = *(const float2*)&bias[t * 2];
        gaml[t * 2] = g.x;  gaml[t * 2 + 1] = g.y;
        betl[t * 2] = b2.x; betl[t * 2 + 1] = b2.y;
        bl[t * 2]   = bo.x; bl[t * 2 + 1]   = bo.y;
    }

    f32x4 acc[8] = {};
    const int sr  = t >> 2;
    const int skz = (((t & 3) ^ (sr & 3)) * 8);

    auto issue = [&](int k0, int buf) {
        if (t < 64)   // 16 rows x 4 chunks = one wave
            async_cp16(&Ab[(size_t)(m0 + sr) * D_ + k0 + skz], &lds[buf * 512]);
#pragma unroll
        for (int p = 0; p < 8; p++)
            async_cp16(&Bt[(size_t)(p * 64 + sr) * D_ + k0 + skz],
                       &lds[1024 + buf * 16384 + (p * 64 + w * 16) * 32]);
    };

    issue(0, 0);
    __syncthreads();

    for (int k0 = 0; k0 < D_; k0 += 32) {
        const int buf = (k0 >> 5) & 1, nbuf = buf ^ 1;
        const int nk = k0 + 32;
        if (nk < D_) issue(nk, nbuf);
        const int ao = buf * 512, bo = 1024 + buf * 16384;
        bf16x8 a = *(const bf16x8*)&lds[ao + ll * 32 + SWZ4(ll, quad)];
#pragma unroll
        for (int in = 0; in < 8; in++) {
            int rb = w * 128 + in * 16 + ll;
            bf16x8 b = *(const bf16x8*)&lds[bo + rb * 32 + SWZ4(rb, quad)];
            acc[in] = __builtin_amdgcn_mfma_f32_16x16x32_bf16(a, b, acc[in], 0, 0, 0);
        }
        __syncthreads();
    }

    // bias + row-stat partials from registers
    float vals[8][4];
    float ps[4] = {}, pq[4] = {};
#pragma unroll
    for (int in = 0; in < 8; in++) {
        int col = w * 128 + in * 16 + ll;
        float bv = bl[col];
#pragma unroll
        for (int r = 0; r < 4; r++) {
            float v = acc[in][r] + bv;
            vals[in][r] = v;
            ps[r] += v;
            pq[r] += v * v;
        }
    }
#pragma unroll
    for (int r = 0; r < 4; r++) {
        float s = ps[r], q = pq[r];
        s += __shfl_xor(s, 1); q += __shfl_xor(q, 1);
        s += __shfl_xor(s, 2); q += __shfl_xor(q, 2);
        s += __shfl_xor(s, 4); q += __shfl_xor(q, 4);
        s += __shfl_xor(s, 8); q += __shfl_xor(q, 8);
        if (ll == 0) {
            int row = quad * 4 + r;
            redS[w][row] = s;
            redQ[w][row] = q;
        }
    }
    __syncthreads();
    if (t < 16) {
        float S = redS[0][t] + redS[1][t] + redS[2][t] + redS[3][t];
        float Q = redQ[0][t] + redQ[1][t] + redQ[2][t] + redQ[3][t];
        float mu  = S * (1.f / 512.f);
        float var = Q * (1.f / 512.f) - mu * mu;
        mv[t][0] = mu;
        mv[t][1] = rsqrtf(var + LN_EPS_);
    }
    __syncthreads();
#pragma unroll
    for (int r = 0; r < 4; r++) {
        int row = quad * 4 + r;
        float mu = mv[row][0], rs = mv[row][1];
#pragma unroll
        for (int in = 0; in < 8; in++) {
            int col = w * 128 + in * 16 + ll;
            Y[(size_t)(m0 + row) * D_ + col] =
                (vals[in][r] - mu) * rs * gaml[col] + betl[col];
        }
    }
}

// ---------------------------------------------------------------------------
extern "C" void kernel_launch(void* const* d_in, const int* in_sizes, int n_in,
                              void* d_out, int out_size, void* d_ws, size_t ws_size,
                              hipStream_t stream)
{
    const float* x    = (const float*)d_in[0];
    const float* Wqkv = (const float*)d_in[1];
    const float* bqkv = (const float*)d_in[2];
    const float* Wout = (const float*)d_in[3];
    const float* bout = (const float*)d_in[4];
    const float* gam  = (const float*)d_in[5];
    const float* bet  = (const float*)d_in[6];
    const float* dl   = (const float*)d_in[7];
    float* out = (float*)d_out;

    const size_t NBHLE = (size_t)B_ * H_ * L_ * E_;       // 2,097,152
    const size_t NG    = (size_t)B_ * H_ * NCH * E_ * E_; // 4,194,304
    const size_t Ng    = (size_t)B_ * H_ * NCH * E_;      // 65,536

    char* p = (char*)d_ws;
    __bf16* Gt  = (__bf16*)p;    p += NG * 2;
    __bf16* Sb  = (__bf16*)p;    p += NG * 2;
    float*  gn  = (float*)p;     p += Ng * 4;
    float*  zl  = (float*)p;     p += Ng * 4;
    __bf16* Qb  = (__bf16*)p;    p += NBHLE * 2;
    __bf16* Kb  = (__bf16*)p;    p += NBHLE * 2;
    __bf16* Vb  = (__bf16*)p;    p += NBHLE * 2;
    __bf16* WqkvT = (__bf16*)p;  p += (size_t)1536 * 512 * 2;
    __bf16* WoutT = (__bf16*)p;  p += (size_t)512 * 512 * 2;
    __bf16* Ao    = (__bf16*)p;  p += NBHLE * 2;               // [4096][512]

    dim3 blk(256);
    k_prep_w      <<<dim3(32, 8),  blk, 0, stream>>>(Wqkv, WqkvT, Wout, WoutT);
    k_mfma_qkv    <<<dim3(12, 64), blk, 0, stream>>>(x, WqkvT, bqkv, Qb, Kb, Vb);
    k_chunk_g     <<<dim3(1024),   blk, 0, stream>>>(Kb, Vb, dl, Gt, gn);
    k_scan_par    <<<dim3(1024),   dim3(64), 0, stream>>>(Gt, gn, dl, Sb, zl);
    k_attn        <<<dim3(1024),   blk, 0, stream>>>(Qb, Kb, Vb, Sb, zl, dl, Ao);
    k_mfma_out_ln <<<dim3(256),    blk, 0, stream>>>(Ao, WoutT, bout, gam, bet, out);
}